// Round 3
// baseline (232.326 us; speedup 1.0000x reference)
//
#include <hip/hip_runtime.h>

// Problem geometry (fixed by the reference): B=8, H=1024, W=1024, periodic.
#define WMASK 1023
#define LOG2W 10
#define HW (1024 * 1024)

#define EPS 1e-6f
#define DT 1e-2f

// Output tile per block and extended (dF) tile with halo=1.
#define TX 64
#define TY 16
#define EX (TX + 2)   // 66
#define EY (TY + 2)   // 18

__device__ __forceinline__ float scal(const float* __restrict__ p) {
    return fabsf(p[0]) + 0.001f;
}
__device__ __forceinline__ float logm(float m) {
    // jnp.log(jnp.where(m < eps, eps, m))
    return logf(m < EPS ? EPS : m);
}
__device__ __forceinline__ float clip01(float v) {
    return fminf(fmaxf(v, 0.0f), 1.0f);
}

// Fully fused: one kernel, no global workspace.
// Phase 1: compute dF_dcv/dF_dci on the (EX x EY) extended tile into LDS;
//          write eta_new for interior points (needs only 1-ring).
// Phase 2: 5-pt stencil over the LDS dF tiles -> cv_new, ci_new.
__global__ __launch_bounds__(256) void irr_fused(
    const float* __restrict__ cv,
    const float* __restrict__ ci,
    const float* __restrict__ eta,
    const float* __restrict__ p_ev,
    const float* __restrict__ p_ei,
    const float* __restrict__ p_kbt,
    const float* __restrict__ p_kv,
    const float* __restrict__ p_ki,
    const float* __restrict__ p_ke,
    const float* __restrict__ p_dv,
    const float* __restrict__ p_di,
    const float* __restrict__ p_L,
    float* __restrict__ cv_new,
    float* __restrict__ ci_new,
    float* __restrict__ eta_new)
{
    __shared__ float sdv[EY][EX];
    __shared__ float sdi[EY][EX];

    const int tid = threadIdx.y * 64 + threadIdx.x;
    const int x0 = blockIdx.x * TX;
    const int y0 = blockIdx.y * TY;
    const int bbase = blockIdx.z * HW;

    // Scalars (uniform address -> scalar cached broadcast loads).
    const float energy_v = scal(p_ev);
    const float energy_i = scal(p_ei);
    const float kBT      = scal(p_kbt);
    const float kappa_v  = scal(p_kv);
    const float kappa_i  = scal(p_ki);
    const float kappa_e  = scal(p_ke);
    const float diff_v   = scal(p_dv);
    const float diff_i   = scal(p_di);
    const float L        = scal(p_L);

    // ---- Phase 1: dF fields on extended tile ----
    for (int t = tid; t < EX * EY; t += 256) {
        const int ex = t % EX;
        const int ey = t / EX;
        const int gx = (x0 + ex - 1) & WMASK;
        const int gy = (y0 + ey - 1) & WMASK;
        const int row  = bbase + (gy << LOG2W);
        const int rowm = bbase + (((gy + WMASK) & WMASK) << LOG2W);
        const int rowp = bbase + (((gy + 1) & WMASK) << LOG2W);
        const int xm = (gx + WMASK) & WMASK;
        const int xp = (gx + 1) & WMASK;

        const float c0 = cv[row + gx];
        const float lap_cv = cv[row + xm] + cv[row + xp]
                           + cv[rowm + gx] + cv[rowp + gx] - 4.0f * c0;
        const float i0 = ci[row + gx];
        const float lap_ci = ci[row + xm] + ci[row + xp]
                           + ci[rowm + gx] + ci[rowp + gx] - 4.0f * i0;
        const float e0 = eta[row + gx];
        const float lap_eta = eta[row + xm] + eta[row + xp]
                            + eta[rowm + gx] + eta[rowp + gx] - 4.0f * e0;

        const float h  = (e0 - 1.0f) * (e0 - 1.0f);
        const float jj = e0 * e0;
        const float cs = 1.0f - c0 - i0;
        const float lcv = logm(c0);
        const float lci = logm(i0);
        const float lcs = logm(cs);

        const float fs = energy_v * c0 + energy_i * i0
                       + kBT * (c0 * lcv + i0 * lci + cs * lcs);
        const float dfs_dcv = energy_v + kBT * (lcv - lcs);
        const float dfs_dci = energy_i + kBT * (lci - lcs);

        const float fv = (c0 - 1.0f) * (c0 - 1.0f) + i0 * i0;
        const float dfv_dcv = 2.0f * (c0 - 1.0f);
        const float dfv_dci = 2.0f * i0;

        sdv[ey][ex] = h * dfs_dcv + jj * dfv_dcv - kappa_v * lap_cv;
        sdi[ey][ex] = h * dfs_dci + jj * dfv_dci - kappa_i * lap_ci;

        // eta_new needs only the 1-ring: finish it here for interior points.
        if (ex >= 1 && ex <= TX && ey >= 1 && ey <= TY) {
            const float dF_deta = fs * 2.0f * (e0 - 1.0f) + fv * 2.0f * e0
                                - kappa_e * lap_eta;   // N_PARAM == 1.0
            eta_new[row + gx] = clip01(e0 + DT * (-L * dF_deta));
        }
    }

    __syncthreads();

    // ---- Phase 2: second 5-pt stencil from LDS ----
    const int tx = threadIdx.x;  // 0..63
    for (int ty = threadIdx.y; ty < TY; ty += 4) {
        const int ex = tx + 1;
        const int ey = ty + 1;

        const float v0 = sdv[ey][ex];
        const float lap_v = sdv[ey][ex - 1] + sdv[ey][ex + 1]
                          + sdv[ey - 1][ex] + sdv[ey + 1][ex] - 4.0f * v0;
        const float w0 = sdi[ey][ex];
        const float lap_i = sdi[ey][ex - 1] + sdi[ey][ex + 1]
                          + sdi[ey - 1][ex] + sdi[ey + 1][ex] - 4.0f * w0;

        const int gidx = bbase + ((y0 + ty) << LOG2W) + (x0 + tx);
        const float c0 = cv[gidx];
        const float i0 = ci[gidx];

        const float mv = diff_v * c0 / kBT;
        const float mi = diff_i * i0 / kBT;

        cv_new[gidx] = clip01(c0 + DT * (mv * lap_v));
        ci_new[gidx] = clip01(i0 + DT * (mi * lap_i));
    }
}

extern "C" void kernel_launch(void* const* d_in, const int* in_sizes, int n_in,
                              void* d_out, int out_size, void* d_ws, size_t ws_size,
                              hipStream_t stream) {
    // Input order: cv, ci, eta, energy_v0, energy_i0, kBT0, kappa_v0, kappa_i0,
    //              kappa_eta0, diff_v0, diff_i0, L0  — all float32 per reference.
    const float* cv  = (const float*)d_in[0];
    const float* ci  = (const float*)d_in[1];
    const float* eta = (const float*)d_in[2];
    const float* p_ev  = (const float*)d_in[3];
    const float* p_ei  = (const float*)d_in[4];
    const float* p_kbt = (const float*)d_in[5];
    const float* p_kv  = (const float*)d_in[6];
    const float* p_ki  = (const float*)d_in[7];
    const float* p_ke  = (const float*)d_in[8];
    const float* p_dv  = (const float*)d_in[9];
    const float* p_di  = (const float*)d_in[10];
    const float* p_L   = (const float*)d_in[11];

    const int N = in_sizes[0];  // 8*1024*1024

    float* out     = (float*)d_out;
    float* cv_new  = out;
    float* ci_new  = out + N;
    float* eta_new = out + 2 * N;

    const dim3 block(64, 4, 1);
    const dim3 grid(1024 / TX, 1024 / TY, N / HW);  // (16, 64, 8)

    irr_fused<<<grid, block, 0, stream>>>(cv, ci, eta, p_ev, p_ei, p_kbt,
                                          p_kv, p_ki, p_ke, p_dv, p_di, p_L,
                                          cv_new, ci_new, eta_new);
}

// Round 4
// 208.321 us; speedup vs baseline: 1.1152x; 1.1152x over previous
//
#include <hip/hip_runtime.h>

// Problem geometry (fixed by the reference): B=8, H=1024, W=1024, periodic.
#define WMASK 1023
#define LOG2W 10
#define HW (1024 * 1024)

#define EPS 1e-6f
#define DT 1e-2f

// Output tile 64x16. Raw fields staged with halo-2 (x padded to float4 align).
#define TX 64
#define TY 16
#define RX 72          // raw LDS row stride: x0-4 .. x0+67
#define RY 20          // y0-2 .. y0+17
#define DXT 66         // dF tile: x0-1 .. x0+64
#define DYT 18         // y0-1 .. y0+16

__device__ __forceinline__ float scal(const float* __restrict__ p) {
    return fabsf(p[0]) + 0.001f;
}
__device__ __forceinline__ float logm(float m) {
    // jnp.log(jnp.where(m < eps, eps, m)) ; fast hw log is ~1e-5 abs err, fine vs 2e-2 thr
    return __logf(m < EPS ? EPS : m);
}
__device__ __forceinline__ float clip01(float v) {
    return fminf(fmaxf(v, 0.0f), 1.0f);
}

__global__ __launch_bounds__(256) void irr_fused(
    const float* __restrict__ cv,
    const float* __restrict__ ci,
    const float* __restrict__ eta,
    const float* __restrict__ p_ev,
    const float* __restrict__ p_ei,
    const float* __restrict__ p_kbt,
    const float* __restrict__ p_kv,
    const float* __restrict__ p_ki,
    const float* __restrict__ p_ke,
    const float* __restrict__ p_dv,
    const float* __restrict__ p_di,
    const float* __restrict__ p_L,
    float* __restrict__ cv_new,
    float* __restrict__ ci_new,
    float* __restrict__ eta_new)
{
    __shared__ float scv[RY][RX];
    __shared__ float sci[RY][RX];
    __shared__ float seta[RY][RX];
    __shared__ float sdv[DYT][DXT];
    __shared__ float sdi[DYT][DXT];

    const int tid = threadIdx.x;
    const int x0 = blockIdx.x * TX;
    const int y0 = blockIdx.y * TY;
    const int bbase = blockIdx.z * HW;

    const float energy_v = scal(p_ev);
    const float energy_i = scal(p_ei);
    const float kBT      = scal(p_kbt);
    const float kappa_v  = scal(p_kv);
    const float kappa_i  = scal(p_ki);
    const float kappa_e  = scal(p_ke);
    const float diff_v   = scal(p_dv);
    const float diff_i   = scal(p_di);
    const float L        = scal(p_L);
    const float rv = diff_v / kBT;     // hoisted: mv = rv * c0
    const float ri = diff_i / kBT;

    // ---- Stage raw fields into LDS with float4 coalesced loads ----
    // 18 float4-chunks per row x 20 rows = 360 chunks per field; pad field
    // stride to 384 (=6*64) so each wave's field index is uniform.
    for (int t = tid; t < 3 * 384; t += 256) {
        const int f = t / 384;
        const int r = t - f * 384;
        if (r < 360) {
            const int cx = r % 18;
            const int cy = r / 18;
            const int gx = (x0 - 4 + cx * 4) & WMASK;   // stays 4-aligned, no row-cross
            const int gy = (y0 - 2 + cy) & WMASK;
            const float* __restrict__ src = (f == 0) ? cv : (f == 1) ? ci : eta;
            const float4 v = *(const float4*)(src + bbase + (gy << LOG2W) + gx);
            float* dst = (f == 0) ? &scv[cy][cx * 4]
                       : (f == 1) ? &sci[cy][cx * 4]
                                  : &seta[cy][cx * 4];
            *(float4*)dst = v;
        }
    }
    __syncthreads();

    // ---- Phase 1: dF fields on the 66x18 extended tile (from LDS) ----
    for (int t = tid; t < DXT * DYT; t += 256) {
        const int ex = t % DXT;          // global x = x0 + ex - 1
        const int ey = t / DXT;          // global y = y0 + ey - 1
        const int rx = ex + 3;           // raw LDS coords
        const int ry = ey + 1;

        const float c0 = scv[ry][rx];
        const float lap_cv = scv[ry][rx - 1] + scv[ry][rx + 1]
                           + scv[ry - 1][rx] + scv[ry + 1][rx] - 4.0f * c0;
        const float i0 = sci[ry][rx];
        const float lap_ci = sci[ry][rx - 1] + sci[ry][rx + 1]
                           + sci[ry - 1][rx] + sci[ry + 1][rx] - 4.0f * i0;
        const float e0 = seta[ry][rx];
        const float lap_eta = seta[ry][rx - 1] + seta[ry][rx + 1]
                            + seta[ry - 1][rx] + seta[ry + 1][rx] - 4.0f * e0;

        const float h  = (e0 - 1.0f) * (e0 - 1.0f);
        const float jj = e0 * e0;
        const float cs = 1.0f - c0 - i0;
        const float lcv = logm(c0);
        const float lci = logm(i0);
        const float lcs = logm(cs);

        const float fs = energy_v * c0 + energy_i * i0
                       + kBT * (c0 * lcv + i0 * lci + cs * lcs);
        const float dfs_dcv = energy_v + kBT * (lcv - lcs);
        const float dfs_dci = energy_i + kBT * (lci - lcs);

        const float fv = (c0 - 1.0f) * (c0 - 1.0f) + i0 * i0;

        sdv[ey][ex] = h * dfs_dcv + jj * (2.0f * (c0 - 1.0f)) - kappa_v * lap_cv;
        sdi[ey][ex] = h * dfs_dci + jj * (2.0f * i0)          - kappa_i * lap_ci;

        // eta_new needs only the 1-ring: finish it for interior points here.
        if (ex >= 1 && ex <= TX && ey >= 1 && ey <= TY) {
            const float dF_deta = fs * 2.0f * (e0 - 1.0f) + fv * 2.0f * e0
                                - kappa_e * lap_eta;   // N_PARAM == 1.0
            const int gidx = bbase + ((y0 + ey - 1) << LOG2W) + (x0 + ex - 1);
            __builtin_nontemporal_store(clip01(e0 + DT * (-L * dF_deta)),
                                        &eta_new[gidx]);
        }
    }
    __syncthreads();

    // ---- Phase 2: second 5-pt stencil over the LDS dF tiles ----
    for (int t = tid; t < TX * TY; t += 256) {
        const int ox = t & (TX - 1);
        const int oy = t >> 6;
        const int ex = ox + 1;
        const int ey = oy + 1;

        const float v0 = sdv[ey][ex];
        const float lap_v = sdv[ey][ex - 1] + sdv[ey][ex + 1]
                          + sdv[ey - 1][ex] + sdv[ey + 1][ex] - 4.0f * v0;
        const float w0 = sdi[ey][ex];
        const float lap_i = sdi[ey][ex - 1] + sdi[ey][ex + 1]
                          + sdi[ey - 1][ex] + sdi[ey + 1][ex] - 4.0f * w0;

        const float c0 = scv[oy + 2][ox + 4];
        const float i0 = sci[oy + 2][ox + 4];

        const int gidx = bbase + ((y0 + oy) << LOG2W) + (x0 + ox);
        __builtin_nontemporal_store(clip01(c0 + DT * ((rv * c0) * lap_v)), &cv_new[gidx]);
        __builtin_nontemporal_store(clip01(i0 + DT * ((ri * i0) * lap_i)), &ci_new[gidx]);
    }
}

extern "C" void kernel_launch(void* const* d_in, const int* in_sizes, int n_in,
                              void* d_out, int out_size, void* d_ws, size_t ws_size,
                              hipStream_t stream) {
    // Input order: cv, ci, eta, energy_v0, energy_i0, kBT0, kappa_v0, kappa_i0,
    //              kappa_eta0, diff_v0, diff_i0, L0  — all float32 per reference.
    const float* cv  = (const float*)d_in[0];
    const float* ci  = (const float*)d_in[1];
    const float* eta = (const float*)d_in[2];
    const float* p_ev  = (const float*)d_in[3];
    const float* p_ei  = (const float*)d_in[4];
    const float* p_kbt = (const float*)d_in[5];
    const float* p_kv  = (const float*)d_in[6];
    const float* p_ki  = (const float*)d_in[7];
    const float* p_ke  = (const float*)d_in[8];
    const float* p_dv  = (const float*)d_in[9];
    const float* p_di  = (const float*)d_in[10];
    const float* p_L   = (const float*)d_in[11];

    const int N = in_sizes[0];  // 8*1024*1024

    float* out     = (float*)d_out;
    float* cv_new  = out;
    float* ci_new  = out + N;
    float* eta_new = out + 2 * N;

    const dim3 block(256);
    const dim3 grid(1024 / TX, 1024 / TY, N / HW);  // (16, 64, 8)

    irr_fused<<<grid, block, 0, stream>>>(cv, ci, eta, p_ev, p_ei, p_kbt,
                                          p_kv, p_ki, p_ke, p_dv, p_di, p_L,
                                          cv_new, ci_new, eta_new);
}